// Round 8
// baseline (61.855 us; speedup 1.0000x reference)
//
#include <hip/hip_runtime.h>

// Involution1d fully fused: B=16, CH=256, DIM=4096, G=16, K=7, PAD=3,
// hid=64, K*G=112.  setup (f16 weights) -> fused (stage x tile in LDS f16,
// MFMA kerngen, kern in LDS, involution, out).  x read once, out written once.
#define BB   16
#define CHN  256
#define DIMN 4096
#define KK   7
#define PADK 3
#define HID  64
#define KGN  112
#define TLC  128       // columns (locations) per block tile
#define XSTD 69        // xs row stride in u32 (odd -> bank-friendly strided reads)
#define HSTH 138       // hs row stride in halves
#define KSTD 132       // ks row stride in u32
#define BN_EPS 1e-5f

typedef __fp16 half2_t __attribute__((ext_vector_type(2)));
typedef __fp16 half8   __attribute__((ext_vector_type(8)));
typedef float  f32x4   __attribute__((ext_vector_type(4)));

union U32H2 { unsigned int u; half2_t h; };

static __device__ __forceinline__ unsigned int packf(float a, float b) {
    U32H2 t; t.h = __builtin_amdgcn_cvt_pkrtz(a, b); return t.u;
}
static __device__ __forceinline__ half2_t ash2(unsigned int u) { U32H2 t; t.u = u; return t.h; }
static __device__ __forceinline__ __fp16 u16h(unsigned short u) {
    return __builtin_bit_cast(__fp16, u);
}
static __device__ __forceinline__ unsigned short hu16(__fp16 h) {
    return __builtin_bit_cast(unsigned short, h);
}

// ---------------------------------------------------------------------------
// Convert w1 [64][256] and w2 [112][64] to f16 (layout unchanged); BN affine.
__global__ __launch_bounds__(256) void setup_k(
    const float* __restrict__ w1, const float* __restrict__ w2,
    const float* __restrict__ bn_gamma, const float* __restrict__ bn_beta,
    const float* __restrict__ bn_mean,  const float* __restrict__ bn_var,
    __fp16* __restrict__ w1f, __fp16* __restrict__ w2f,
    float* __restrict__ scb, float* __restrict__ shb) {
    int t = blockIdx.x * 256 + threadIdx.x;   // grid covers 16384
    if (t < HID * CHN) w1f[t] = (__fp16)w1[t];
    if (t < KGN * HID) w2f[t] = (__fp16)w2[t];
    if (t < HID) {
        float s = bn_gamma[t] * rsqrtf(bn_var[t] + BN_EPS);
        scb[t] = s;
        shb[t] = bn_beta[t] - bn_mean[t] * s;
    }
}

// ---------------------------------------------------------------------------
// kern row extraction from row-pair-packed uint2 quads (parity OFF = (7g)&1).
// q[i].x = cols c0, q[i].y = c0+1; rows (2*(rpb+i), 2*(rpb+i)+1).
template <int OFF>
static __device__ __forceinline__ void extract2(const uint2 q[4],
                                                float kva[KK], float kvb[KK]) {
#pragma unroll
    for (int k = 0; k < KK; ++k) {
        const int kk = k + OFF;
        const int i  = kk >> 1;
        const int h  = kk & 1;
        half2_t a = ash2(q[i].x);
        half2_t c = ash2(q[i].y);
        kva[k] = h ? (float)a[1] : (float)a[0];
        kvb[k] = h ? (float)c[1] : (float)c[0];
    }
}

// ---------------------------------------------------------------------------
// Fused kernel.  Block = (b, 128-col tile), 8 waves.
//  xs: [256 ch][138 halves], hidx = (dimcol - l0) + 4 (halo 1..3 / 132..134)
//  Phases 1/2: wave w owns cols [16w,16w+16).  Involution: wave w owns
//  ch [32w,32w+32), lane l owns col pair (2l, 2l+1).
// Fragment maps (16x16x32): A[m][k]: m=lane&15, k=8*((lane>>4)&3)+j;
// B[k][n]: n=lane&15; D[m][n]: n=lane&15, m=4*((lane>>4)&3)+reg.
__global__ __launch_bounds__(512, 2) void fused_k(
    const float* __restrict__ x,
    const __fp16* __restrict__ w1f,
    const float* __restrict__ b1,
    const float* __restrict__ scb, const float* __restrict__ shb,
    const __fp16* __restrict__ w2f,
    const float* __restrict__ b2,
    float* __restrict__ out) {
    __shared__ unsigned int   xs[CHN * XSTD];   // 70656 B
    __shared__ unsigned short hs[HID * HSTH];   // 17664 B
    __shared__ unsigned int   ks[56 * KSTD];    // 29568 B   (total 115.1 KiB)

    const int t    = threadIdx.x;          // 0..511
    const int lane = t & 63;
    const int w    = t >> 6;               // wave 0..7
    const int lr   = t & 15;
    const int lg   = (t >> 4) & 3;
    const int b    = blockIdx.x >> 5;
    const int l0   = (blockIdx.x & 31) * TLC;

    unsigned short* xs16 = (unsigned short*)xs;

    // ---- Stage x tile -> LDS f16 (main: 512 B contiguous per row) ----
    {
        const int c  = t & 31;             // col quad: cols 4c..4c+3
        const int rr = t >> 5;             // 0..15
        const float* xg = x + ((size_t)b * CHN + rr) * DIMN + l0 + 4 * c;
#pragma unroll 4
        for (int rd = 0; rd < 16; ++rd) {
            const int row = 16 * rd + rr;
            float4 v = *(const float4*)(xg + (size_t)(16 * rd) * DIMN);
            unsigned int* dst = xs + row * XSTD + 2 * c + 2;
            dst[0] = packf(v.x, v.y);
            dst[1] = packf(v.z, v.w);
        }
        // halo: 3 cols each side (hidx 1..3 and 132..134)
        const int row  = t >> 1;
        const int side = t & 1;
        const float* xrow = x + ((size_t)b * CHN + row) * DIMN;
        if (side == 0) {
#pragma unroll
            for (int j = 0; j < 3; ++j) {
                int dc = l0 - 3 + j;
                float v = (dc >= 0) ? xrow[dc] : 0.0f;
                xs16[row * (2 * XSTD) + 1 + j] = hu16((__fp16)v);
            }
        } else {
#pragma unroll
            for (int j = 0; j < 3; ++j) {
                int dc = l0 + TLC + j;
                float v = (dc < DIMN) ? xrow[dc] : 0.0f;
                xs16[row * (2 * XSTD) + 132 + j] = hu16((__fp16)v);
            }
        }
    }
    __syncthreads();

    const int colL = 16 * w + lr;          // wave's column (0..127)

    // ---- Phase 1: h = w1 . x  (4 o-frags x 8 K-steps) ----
    f32x4 acc[4];
#pragma unroll
    for (int of = 0; of < 4; ++of) acc[of] = (f32x4){0.f, 0.f, 0.f, 0.f};

#pragma unroll
    for (int p = 0; p < 8; ++p) {
        half8 bf;
#pragma unroll
        for (int j = 0; j < 8; ++j)
            bf[j] = u16h(xs16[(32 * p + 8 * lg + j) * (2 * XSTD) + colL + 4]);
#pragma unroll
        for (int of = 0; of < 4; ++of) {
            half8 af = *(const half8*)(w1f + (16 * of + lr) * CHN + 32 * p + 8 * lg);
            acc[of] = __builtin_amdgcn_mfma_f32_16x16x32_f16(af, bf, acc[of], 0, 0, 0);
        }
    }

    // ---- bias + relu + BN; h -> hs (wave-private cols, same-wave consumer)
#pragma unroll
    for (int of = 0; of < 4; ++of) {
#pragma unroll
        for (int r = 0; r < 4; ++r) {
            const int o = 16 * of + 4 * lg + r;
            float hv = fmaxf(acc[of][r] + b1[o], 0.f) * scb[o] + shb[o];
            hs[o * HSTH + colL] = hu16((__fp16)hv);
        }
    }

    // ---- Phase 2: kern = w2 . h  (7 r-frags x 2 K-steps) ----
    f32x4 acc2[7];
#pragma unroll
    for (int rf = 0; rf < 7; ++rf) acc2[rf] = (f32x4){0.f, 0.f, 0.f, 0.f};

#pragma unroll
    for (int kx = 0; kx < 2; ++kx) {
        half8 bf;
#pragma unroll
        for (int j = 0; j < 8; ++j)
            bf[j] = u16h(hs[(32 * kx + 8 * lg + j) * HSTH + colL]);
#pragma unroll
        for (int rf = 0; rf < 7; ++rf) {
            half8 af = *(const half8*)(w2f + (16 * rf + lr) * HID + 32 * kx + 8 * lg);
            acc2[rf] = __builtin_amdgcn_mfma_f32_16x16x32_f16(af, bf, acc2[rf], 0, 0, 0);
        }
    }

    // ---- bias + row-pair pack -> ks LDS
#pragma unroll
    for (int rf = 0; rf < 7; ++rf) {
#pragma unroll
        for (int p = 0; p < 2; ++p) {
            const int r0 = 16 * rf + 4 * lg + 2 * p;
            float k0 = acc2[rf][2 * p + 0] + b2[r0 + 0];
            float k1 = acc2[rf][2 * p + 1] + b2[r0 + 1];
            ks[(r0 >> 1) * KSTD + colL] = packf(k0, k1);
        }
    }
    __syncthreads();

    // ---- Involution: wave w -> ch [32w, 32w+32), lane -> cols (2l, 2l+1) ----
    const int l  = lane;
    const int c0 = 2 * l;
    float* outp = out + ((size_t)b * CHN + 32 * w) * DIMN + l0 + c0;

#pragma unroll
    for (int gi = 0; gi < 2; ++gi) {             // g parity = gi (g = 2w+gi)
        const int g   = 2 * w + gi;
        const int rpb = (7 * g) >> 1;
        uint2 q[4];
#pragma unroll
        for (int ii = 0; ii < 4; ++ii)
            q[ii] = *(const uint2*)(ks + (rpb + ii) * KSTD + c0);
        float kva[KK], kvb[KK];
        if (gi == 0) extract2<0>(q, kva, kvb);
        else         extract2<1>(q, kva, kvb);

#pragma unroll 8
        for (int i2 = 0; i2 < 16; ++i2) {
            const int ch = 32 * w + 16 * gi + i2;
            const unsigned int* xr = xs + ch * XSTD + l;
            unsigned int uu[5];
#pragma unroll
            for (int j = 0; j < 5; ++j) uu[j] = xr[j];
            // rel halves 1..8 (hidx = c0 + rel); taps colA: 1..7, colB: 2..8
            float xv[8];
#pragma unroll
            for (int r = 1; r <= 8; ++r) {
                unsigned int u = uu[r >> 1];
                unsigned short us = (r & 1) ? (unsigned short)(u >> 16)
                                            : (unsigned short)(u & 0xffff);
                xv[r - 1] = (float)u16h(us);
            }
            float o0 = 0.f, o1 = 0.f;
#pragma unroll
            for (int k = 0; k < KK; ++k) {
                o0 = fmaf(kva[k], xv[k],     o0);
                o1 = fmaf(kvb[k], xv[k + 1], o1);
            }
            *(float2*)(outp + (size_t)(16 * gi + i2) * DIMN) = make_float2(o0, o1);
        }
    }
}

// ---------------------------------------------------------------------------
extern "C" void kernel_launch(void* const* d_in, const int* in_sizes, int n_in,
                              void* d_out, int out_size, void* d_ws, size_t ws_size,
                              hipStream_t stream) {
    (void)in_sizes; (void)n_in; (void)out_size; (void)ws_size;

    const float* x        = (const float*)d_in[0];
    const float* w1       = (const float*)d_in[1];
    const float* b1       = (const float*)d_in[2];
    const float* bn_gamma = (const float*)d_in[3];
    const float* bn_beta  = (const float*)d_in[4];
    const float* bn_mean  = (const float*)d_in[5];
    const float* bn_var   = (const float*)d_in[6];
    const float* w2       = (const float*)d_in[7];
    const float* b2       = (const float*)d_in[8];
    float*       out      = (float*)d_out;

    __fp16* w1f = (__fp16*)d_ws;                 // 16384 f16
    __fp16* w2f = w1f + HID * CHN;               // 7168 f16
    float*  scb = (float*)(w2f + KGN * HID);     // 64
    float*  shb = scb + HID;                     // 64

    setup_k<<<(HID * CHN + 255) / 256, 256, 0, stream>>>(
        w1, w2, bn_gamma, bn_beta, bn_mean, bn_var, w1f, w2f, scb, shb);
    fused_k<<<BB * (DIMN / TLC), 512, 0, stream>>>(
        x, w1f, b1, scb, shb, w2f, b2, out);
}